// Round 4
// baseline (66.978 us; speedup 1.0000x reference)
//
#include <hip/hip_runtime.h>
#include <math.h>

namespace {

constexpr int kL       = 2048;  // sequence length
constexpr int kBlkPos  = 64;    // positions per block
constexpr int kThreads = 512;   // 8 waves; each wave handles 8 positions
constexpr int kPosPerWave = kBlkPos / 8;

typedef float    vfloat4 __attribute__((ext_vector_type(4)));
typedef _Float16 half4   __attribute__((ext_vector_type(4)));

// x += dpp_move(x); all-VALU, no LDS.
template <int CTRL, int RM, bool BC>
__device__ __forceinline__ float dpp_acc(float x) {
    const int y = __builtin_amdgcn_update_dpp(0, __float_as_int(x), CTRL, RM, 0xF, BC);
    return x + __int_as_float(y);
}

// Full 64-lane sum, broadcast to all lanes via readlane(63).
__device__ __forceinline__ float wave_sum(float x) {
    x = dpp_acc<0xB1,  0xF, true >(x);  // quad_perm [1,0,3,2]  (xor 1)
    x = dpp_acc<0x4E,  0xF, true >(x);  // quad_perm [2,3,0,1]  (xor 2)
    x = dpp_acc<0x124, 0xF, true >(x);  // row_ror:4
    x = dpp_acc<0x128, 0xF, true >(x);  // row_ror:8 -> 16-lane row sums
    x = dpp_acc<0x142, 0xA, false>(x);  // row_bcast15 -> rows 1,3
    x = dpp_acc<0x143, 0xC, false>(x);  // row_bcast31 -> rows 2,3 (row3 = total)
    return __int_as_float(__builtin_amdgcn_readlane(__float_as_int(x), 63));
}

// One wave per position. Weights in LDS as fp16 [tap][class][half4-lane];
// class 5 is a zero sentinel (padding token / out-of-range tap) -> branchless.
// LayerNorm stats via DPP wave reduce. Mask folded into the epilogue.
__global__ __launch_bounds__(kThreads, 6)
void cnn_emb_ln(const int*   __restrict__ ids,     // [B*L] tokens 0..5
                const float* __restrict__ mask,    // [B*L]
                const float* __restrict__ W3,      // [256][5][3]
                const float* __restrict__ W5,      // [256][5][5]
                const float* __restrict__ W7,      // [256][5][7]
                const float* __restrict__ gamma,   // [768]
                const float* __restrict__ beta,    // [768]
                float*       __restrict__ out)     // [B*L][768]
{
    // taps 0-2: W3 (window j=k+2); 3-7: W5 (j=k+1); 8-14: W7 (j=k)
    __shared__ half4 sW[15][6][64];          // 46.1 KiB
    __shared__ int   scls[kBlkPos + 6];
    __shared__ float smask[kBlkPos];

    const int tid        = threadIdx.x;
    const int block_base = blockIdx.x * kBlkPos;
    const int seq_base   = block_base & ~(kL - 1);

    // ---- stage weights as fp16 (class 5 = zeros) ----
    _Float16* sWh = reinterpret_cast<_Float16*>(sW);
    for (int i = tid; i < 15 * 6 * 256; i += kThreads) {
        const int o = i & 255;
        const int c = (i >> 8) % 6;
        const int t = i / (6 * 256);
        float v = 0.f;
        if (c < 5) {
            if (t < 3)      v = W3[o * 15 + c * 3 + t];
            else if (t < 8) v = W5[o * 25 + c * 5 + (t - 3)];
            else            v = W7[o * 35 + c * 7 + (t - 8)];
        }
        sWh[i] = (_Float16)v;
    }

    // ---- stage classes (halo, sentinel 5) and mask ----
    if (tid < kBlkPos + 6) {
        const int p = block_base - 3 + tid;
        int c = 5;
        if (p >= seq_base && p < seq_base + kL) {
            const int v = ids[p];
            c = (v < 5) ? v : 5;
        }
        scls[tid] = c;
    }
    if (tid < kBlkPos) smask[tid] = mask[block_base + tid];

    const int lane = tid & 63;
    const int wave = tid >> 6;

    // per-lane gamma/beta (channels 4*lane..+3 per group) held as fp16: 12 VGPRs
    half4 gh[3], bh[3];
    #pragma unroll
    for (int g = 0; g < 3; ++g) {
        const float4 gg = *reinterpret_cast<const float4*>(gamma + g * 256 + 4 * lane);
        const float4 bb = *reinterpret_cast<const float4*>(beta  + g * 256 + 4 * lane);
        gh[g] = half4{(_Float16)gg.x, (_Float16)gg.y, (_Float16)gg.z, (_Float16)gg.w};
        bh[g] = half4{(_Float16)bb.x, (_Float16)bb.y, (_Float16)bb.z, (_Float16)bb.w};
    }

    __syncthreads();

    const int wloc = wave * kPosPerWave;

    #pragma unroll 2
    for (int i = 0; i < kPosPerWave; ++i) {
        const int li = wloc + i;

        int cw[7];
        #pragma unroll
        for (int j = 0; j < 7; ++j) cw[j] = scls[li + j];
        const float m = smask[li];

        // branchless tap accumulation in packed fp16 (v_pk_add_f16)
        const half4 a3 =  sW[0][cw[2]][lane] + sW[1][cw[3]][lane] + sW[2][cw[4]][lane];
        const half4 a5 = (sW[3][cw[1]][lane] + sW[4][cw[2]][lane])
                       + (sW[5][cw[3]][lane] + sW[6][cw[4]][lane]) + sW[7][cw[5]][lane];
        const half4 a7 = ((sW[ 8][cw[0]][lane] + sW[ 9][cw[1]][lane])
                       +  (sW[10][cw[2]][lane] + sW[11][cw[3]][lane]))
                       + ((sW[12][cw[4]][lane] + sW[13][cw[5]][lane]) + sW[14][cw[6]][lane]);

        const float4 h3 = {(float)a3.x, (float)a3.y, (float)a3.z, (float)a3.w};
        const float4 h5 = {(float)a5.x, (float)a5.y, (float)a5.z, (float)a5.w};
        const float4 h7 = {(float)a7.x, (float)a7.y, (float)a7.z, (float)a7.w};

        // raw stats (mask folded in after the reduce)
        float s = ((h3.x + h3.y) + (h3.z + h3.w))
                + ((h5.x + h5.y) + (h5.z + h5.w))
                + ((h7.x + h7.y) + (h7.z + h7.w));
        float ss =            h3.x * h3.x;
        ss = fmaf(h3.y, h3.y, ss); ss = fmaf(h3.z, h3.z, ss); ss = fmaf(h3.w, h3.w, ss);
        ss = fmaf(h5.x, h5.x, ss); ss = fmaf(h5.y, h5.y, ss); ss = fmaf(h5.z, h5.z, ss);
        ss = fmaf(h5.w, h5.w, ss); ss = fmaf(h7.x, h7.x, ss); ss = fmaf(h7.y, h7.y, ss);
        ss = fmaf(h7.z, h7.z, ss); ss = fmaf(h7.w, h7.w, ss);

        const float s_tot  = wave_sum(s);
        const float ss_tot = wave_sum(ss);

        const float inv_n = 1.0f / 768.0f;
        const float mu  = m * s_tot * inv_n;
        const float ex2 = (m * m) * ss_tot * inv_n;
        const float var = fmaxf(ex2 - mu * mu, 0.0f);
        const float rs  = rsqrtf(var + 1e-12f);
        const float aa  = m * rs;        // (m*h - mu)*rs = h*aa + cc
        const float cc  = -mu * rs;

        float* o = out + (size_t)(block_base + li) * 768 + 4 * lane;

        vfloat4 r;
        r.x = fmaf(fmaf(h3.x, aa, cc), (float)gh[0].x, (float)bh[0].x);
        r.y = fmaf(fmaf(h3.y, aa, cc), (float)gh[0].y, (float)bh[0].y);
        r.z = fmaf(fmaf(h3.z, aa, cc), (float)gh[0].z, (float)bh[0].z);
        r.w = fmaf(fmaf(h3.w, aa, cc), (float)gh[0].w, (float)bh[0].w);
        __builtin_nontemporal_store(r, reinterpret_cast<vfloat4*>(o));

        r.x = fmaf(fmaf(h5.x, aa, cc), (float)gh[1].x, (float)bh[1].x);
        r.y = fmaf(fmaf(h5.y, aa, cc), (float)gh[1].y, (float)bh[1].y);
        r.z = fmaf(fmaf(h5.z, aa, cc), (float)gh[1].z, (float)bh[1].z);
        r.w = fmaf(fmaf(h5.w, aa, cc), (float)gh[1].w, (float)bh[1].w);
        __builtin_nontemporal_store(r, reinterpret_cast<vfloat4*>(o + 256));

        r.x = fmaf(fmaf(h7.x, aa, cc), (float)gh[2].x, (float)bh[2].x);
        r.y = fmaf(fmaf(h7.y, aa, cc), (float)gh[2].y, (float)bh[2].y);
        r.z = fmaf(fmaf(h7.z, aa, cc), (float)gh[2].z, (float)bh[2].z);
        r.w = fmaf(fmaf(h7.w, aa, cc), (float)gh[2].w, (float)bh[2].w);
        __builtin_nontemporal_store(r, reinterpret_cast<vfloat4*>(o + 512));
    }
}

} // namespace

extern "C" void kernel_launch(void* const* d_in, const int* in_sizes, int n_in,
                              void* d_out, int out_size, void* d_ws, size_t ws_size,
                              hipStream_t stream) {
    const int*   ids   = (const int*)  d_in[0];
    const float* mask  = (const float*)d_in[1];
    const float* W3    = (const float*)d_in[2];
    const float* W5    = (const float*)d_in[3];
    const float* W7    = (const float*)d_in[4];
    const float* gamma = (const float*)d_in[5];
    const float* beta  = (const float*)d_in[6];
    float*       out   = (float*)d_out;

    const int npos = in_sizes[0];              // B*L = 65536
    const int grid = npos / kBlkPos;           // 1024 blocks, 3/CU (46.6 KiB LDS)

    hipLaunchKernelGGL(cnn_emb_ln, dim3(grid), dim3(kThreads), 0, stream,
                       ids, mask, W3, W5, W7, gamma, beta, out);
}

// Round 5
// 48.426 us; speedup vs baseline: 1.3831x; 1.3831x over previous
//
#include <hip/hip_runtime.h>
#include <math.h>

namespace {

constexpr int kL       = 2048;  // sequence length
constexpr int kThreads = 512;   // 8 waves
constexpr int kBlkPos  = 64;    // 8 waves x 8 positions per block

typedef float    vfloat4 __attribute__((ext_vector_type(4)));
typedef _Float16 half4   __attribute__((ext_vector_type(4)));

// x += dpp_move(x); all-VALU, no LDS.
template <int CTRL, int RM, bool BC>
__device__ __forceinline__ float dpp_acc(float x) {
    const int y = __builtin_amdgcn_update_dpp(0, __float_as_int(x), CTRL, RM, 0xF, BC);
    return x + __int_as_float(y);
}

// Full 64-lane sum, result broadcast via readlane(63).
__device__ __forceinline__ float wave_sum(float x) {
    x = dpp_acc<0xB1,  0xF, true >(x);  // quad_perm xor1
    x = dpp_acc<0x4E,  0xF, true >(x);  // quad_perm xor2
    x = dpp_acc<0x124, 0xF, true >(x);  // row_ror:4
    x = dpp_acc<0x128, 0xF, true >(x);  // row_ror:8 -> row sums
    x = dpp_acc<0x142, 0xA, false>(x);  // row_bcast15 -> rows 1,3
    x = dpp_acc<0x143, 0xC, false>(x);  // row_bcast31 -> row 3 = total
    return __int_as_float(__builtin_amdgcn_readlane(__float_as_int(x), 63));
}

__device__ __forceinline__ int wrow(int t, int c) {  // weight-table row
    return (c == 5) ? 75 : (t * 5 + c);
}

// One wave per position (8 consecutive positions per wave). Single fp16
// weight table in LDS: row = tap*5+class, row 75 = zeros (sentinel: token 5
// or out-of-range tap). Window classes distributed via readlane from a
// per-wave halo register. LayerNorm stats via DPP; mask folded analytically.
__global__ __launch_bounds__(kThreads, 4)
void cnn_emb_ln(const int*   __restrict__ ids,     // [B*L] tokens 0..5
                const float* __restrict__ mask,    // [B*L]
                const float* __restrict__ W3,      // [256][5][3]
                const float* __restrict__ W5,      // [256][5][5]
                const float* __restrict__ W7,      // [256][5][7]
                const float* __restrict__ gamma,   // [768]
                const float* __restrict__ beta,    // [768]
                float*       __restrict__ out)     // [B*L][768]
{
    __shared__ half4 sW[76][64];   // 38912 B

    const int tid  = threadIdx.x;
    const int lane = tid & 63;
    const int wave = tid >> 6;

    // ---- stage weights: coalesced float4 reads, scattered fp16 LDS writes ----
    _Float16* sWh = reinterpret_cast<_Float16*>(sW);
    if (tid < 256) sWh[75 * 256 + tid] = (_Float16)0.f;     // zero sentinel row

    {   // W3: 3840 floats, taps 0..2
        const float4* v4 = reinterpret_cast<const float4*>(W3);
        for (int i = tid; i < 960; i += kThreads) {
            const float4 v = v4[i];
            const float f[4] = {v.x, v.y, v.z, v.w};
            #pragma unroll
            for (int j = 0; j < 4; ++j) {
                const int e = 4 * i + j, o = e / 15, r = e % 15;
                sWh[((r % 3) * 5 + (r / 3)) * 256 + o] = (_Float16)f[j];
            }
        }
    }
    {   // W5: 6400 floats, taps 3..7
        const float4* v4 = reinterpret_cast<const float4*>(W5);
        for (int i = tid; i < 1600; i += kThreads) {
            const float4 v = v4[i];
            const float f[4] = {v.x, v.y, v.z, v.w};
            #pragma unroll
            for (int j = 0; j < 4; ++j) {
                const int e = 4 * i + j, o = e / 25, r = e % 25;
                sWh[((3 + r % 5) * 5 + (r / 5)) * 256 + o] = (_Float16)f[j];
            }
        }
    }
    {   // W7: 8960 floats, taps 8..14
        const float4* v4 = reinterpret_cast<const float4*>(W7);
        for (int i = tid; i < 2240; i += kThreads) {
            const float4 v = v4[i];
            const float f[4] = {v.x, v.y, v.z, v.w};
            #pragma unroll
            for (int j = 0; j < 4; ++j) {
                const int e = 4 * i + j, o = e / 35, r = e % 35;
                sWh[((8 + r % 7) * 5 + (r / 7)) * 256 + o] = (_Float16)f[j];
            }
        }
    }

    // ---- per-wave id halo (14) + mask (8) into lane registers ----
    const int p0 = blockIdx.x * kBlkPos + wave * 8;   // first position of wave
    const int l0 = p0 & (kL - 1);

    int myc = 5;
    if (lane < 14) {
        const int lp = l0 - 3 + lane;
        if (lp >= 0 && lp < kL) {
            const int v = ids[p0 - 3 + lane];
            myc = (v < 5) ? v : 5;
        }
    }
    float mym = 0.f;
    if (lane < 8) mym = mask[p0 + lane];

    // per-lane gamma/beta, fp32 in registers
    float ga[3][4], be[3][4];
    #pragma unroll
    for (int g = 0; g < 3; ++g) {
        const float4 gg = *reinterpret_cast<const float4*>(gamma + g * 256 + 4 * lane);
        const float4 bb = *reinterpret_cast<const float4*>(beta  + g * 256 + 4 * lane);
        ga[g][0] = gg.x; ga[g][1] = gg.y; ga[g][2] = gg.z; ga[g][3] = gg.w;
        be[g][0] = bb.x; be[g][1] = bb.y; be[g][2] = bb.z; be[g][3] = bb.w;
    }

    __syncthreads();

    #pragma unroll
    for (int i = 0; i < 8; ++i) {
        // wave-uniform window classes + mask via readlane (immediate lanes)
        int c[7];
        #pragma unroll
        for (int j = 0; j < 7; ++j) c[j] = __builtin_amdgcn_readlane(myc, i + j);
        const float m = __int_as_float(__builtin_amdgcn_readlane(__float_as_int(mym), i));

        // branchless tap accumulation, packed fp16
        const half4 a3 =  sW[wrow(0, c[2])][lane] + sW[wrow(1, c[3])][lane]
                       +  sW[wrow(2, c[4])][lane];
        const half4 a5 = (sW[wrow(3, c[1])][lane] + sW[wrow(4, c[2])][lane])
                       + (sW[wrow(5, c[3])][lane] + sW[wrow(6, c[4])][lane])
                       +  sW[wrow(7, c[5])][lane];
        const half4 a7 = ((sW[wrow( 8, c[0])][lane] + sW[wrow( 9, c[1])][lane])
                       +  (sW[wrow(10, c[2])][lane] + sW[wrow(11, c[3])][lane]))
                       + ((sW[wrow(12, c[4])][lane] + sW[wrow(13, c[5])][lane])
                       +   sW[wrow(14, c[6])][lane]);

        const float h3[4] = {(float)a3.x, (float)a3.y, (float)a3.z, (float)a3.w};
        const float h5[4] = {(float)a5.x, (float)a5.y, (float)a5.z, (float)a5.w};
        const float h7[4] = {(float)a7.x, (float)a7.y, (float)a7.z, (float)a7.w};

        // raw stats; mask folded in after the reduce
        float s = ((h3[0] + h3[1]) + (h3[2] + h3[3]))
                + ((h5[0] + h5[1]) + (h5[2] + h5[3]))
                + ((h7[0] + h7[1]) + (h7[2] + h7[3]));
        float ss = h3[0] * h3[0];
        ss = fmaf(h3[1], h3[1], ss); ss = fmaf(h3[2], h3[2], ss); ss = fmaf(h3[3], h3[3], ss);
        ss = fmaf(h5[0], h5[0], ss); ss = fmaf(h5[1], h5[1], ss); ss = fmaf(h5[2], h5[2], ss);
        ss = fmaf(h5[3], h5[3], ss); ss = fmaf(h7[0], h7[0], ss); ss = fmaf(h7[1], h7[1], ss);
        ss = fmaf(h7[2], h7[2], ss); ss = fmaf(h7[3], h7[3], ss);

        const float s_tot  = wave_sum(s);
        const float ss_tot = wave_sum(ss);

        const float inv_n = 1.0f / 768.0f;
        const float mu  = m * s_tot * inv_n;
        const float ex2 = (m * m) * ss_tot * inv_n;
        const float var = fmaxf(ex2 - mu * mu, 0.0f);
        const float rs  = rsqrtf(var + 1e-12f);
        const float aa  = m * rs;          // (m*h - mu)*rs = h*aa + cc
        const float cc  = -mu * rs;

        float* o = out + (size_t)(p0 + i) * 768 + 4 * lane;

        vfloat4 r;
        r.x = fmaf(fmaf(h3[0], aa, cc), ga[0][0], be[0][0]);
        r.y = fmaf(fmaf(h3[1], aa, cc), ga[0][1], be[0][1]);
        r.z = fmaf(fmaf(h3[2], aa, cc), ga[0][2], be[0][2]);
        r.w = fmaf(fmaf(h3[3], aa, cc), ga[0][3], be[0][3]);
        __builtin_nontemporal_store(r, reinterpret_cast<vfloat4*>(o));

        r.x = fmaf(fmaf(h5[0], aa, cc), ga[1][0], be[1][0]);
        r.y = fmaf(fmaf(h5[1], aa, cc), ga[1][1], be[1][1]);
        r.z = fmaf(fmaf(h5[2], aa, cc), ga[1][2], be[1][2]);
        r.w = fmaf(fmaf(h5[3], aa, cc), ga[1][3], be[1][3]);
        __builtin_nontemporal_store(r, reinterpret_cast<vfloat4*>(o + 256));

        r.x = fmaf(fmaf(h7[0], aa, cc), ga[2][0], be[2][0]);
        r.y = fmaf(fmaf(h7[1], aa, cc), ga[2][1], be[2][1]);
        r.z = fmaf(fmaf(h7[2], aa, cc), ga[2][2], be[2][2]);
        r.w = fmaf(fmaf(h7[3], aa, cc), ga[2][3], be[2][3]);
        __builtin_nontemporal_store(r, reinterpret_cast<vfloat4*>(o + 512));
    }
}

} // namespace

extern "C" void kernel_launch(void* const* d_in, const int* in_sizes, int n_in,
                              void* d_out, int out_size, void* d_ws, size_t ws_size,
                              hipStream_t stream) {
    const int*   ids   = (const int*)  d_in[0];
    const float* mask  = (const float*)d_in[1];
    const float* W3    = (const float*)d_in[2];
    const float* W5    = (const float*)d_in[3];
    const float* W7    = (const float*)d_in[4];
    const float* gamma = (const float*)d_in[5];
    const float* beta  = (const float*)d_in[6];
    float*       out   = (float*)d_out;

    const int npos = in_sizes[0];              // B*L = 65536
    const int grid = npos / kBlkPos;           // 1024 blocks; 2/CU -> 2 clean rounds

    hipLaunchKernelGGL(cnn_emb_ln, dim3(grid), dim3(kThreads), 0, stream,
                       ids, mask, W3, W5, W7, gamma, beta, out);
}